// Round 14
// baseline (177.344 us; speedup 1.0000x reference)
//
#include <hip/hip_runtime.h>
#include <cstdint>

#define NT   1024
#define NBIN 4096
#define CAP  3584   // candidate buffer (u64)
#define KCAP 2048   // sort set (u64), power of two
#define ZCAP 16     // zero-q index list

// monotone float -> uint key (ascending)
__device__ __forceinline__ unsigned f2key(float x) {
  unsigned u = __float_as_uint(x);
  return (u & 0x80000000u) ? ~u : (u | 0x80000000u);
}
__device__ __forceinline__ float key2f(unsigned kb) {
  unsigned u = (kb & 0x80000000u) ? (kb & 0x7FFFFFFFu) : ~kb;
  return __uint_as_float(u);
}

// Find largest bin b with inclusive suffix sum >= target. All threads call.
__device__ void suffix_find(const unsigned* h, int target, int tid,
                            unsigned* s_part, int* s_res, int* s_above) {
  if (tid < 64) {
    unsigned sum = 0;
    int base = tid * 64;
    for (int b = 0; b < 64; ++b) sum += h[base + b];
    s_part[tid] = sum;
  }
  __syncthreads();
  if (tid == 0) {
    long long acc = 0; int res = 0; long long above = 0; int seg = -1;
    for (int sg = 63; sg >= 0; --sg) {
      if (acc + (long long)s_part[sg] >= (long long)target) { seg = sg; break; }
      acc += s_part[sg];
    }
    if (seg >= 0) {
      int base = seg * 64;
      for (int b = 63; b >= 0; --b) {
        if (acc + (long long)h[base + b] >= (long long)target) { res = base + b; above = acc; break; }
        acc += h[base + b];
      }
    }
    *s_res = res;
    *s_above = (int)above;
  }
  __syncthreads();
}

__global__ __launch_bounds__(NT) void topk_topp_sample_kernel(
    const float* __restrict__ logits, const void* __restrict__ kraw,
    const float* __restrict__ parr, const float* __restrict__ qarr,
    int* __restrict__ out, int V) {
  const int r   = blockIdx.x;
  const int tid = threadIdx.x;
  const size_t rowoff = (size_t)r * (size_t)V;
  const float* lrow = logits + rowoff;
  const float* qrow = qarr + rowoff;

  __shared__ unsigned s_hist[NBIN];                 // 16 KB (reused as s_e + reduce bufs)
  __shared__ unsigned long long s_cand[CAP];        // 28 KB
  __shared__ unsigned long long s_kept[KCAP];       // 16 KB
  __shared__ unsigned s_part[64];
  __shared__ float s_Z2;
  __shared__ int s_cnt, s_cnt2, s_b1, s_a1, s_b2, s_a2, s_start, s_jstar;
  __shared__ int s_nzq, s_zq[ZCAP], s_nanIdx;

  // k dtype auto-detect (k in [1,1024), never 0): int64 buffer has k[0]'s
  // high word (== 0) at int32 index 1; int32 buffer has k[1] >= 1 there.
  const int* k32 = (const int*)kraw;
  int k;
  if (k32[1] == 0) k = (int)((const long long*)kraw)[r];
  else             k = k32[r];
  if (k < 1) k = 1;
  if (k > KCAP - 8) k = KCAP - 8;
  const float oneMinusP = 1.0f - parr[r];

  for (int b = tid; b < NBIN; b += NT) s_hist[b] = 0;
  if (tid == 0) { s_cnt = 0; s_cnt2 = 0; s_nzq = 0; }
  __syncthreads();

  // ---- Pass 1: 12-bit key histogram ----
  const float4* lrow4 = (const float4*)lrow;
  const int n4 = V >> 2;
  for (int j = tid; j < n4; j += NT) {
    float4 v = lrow4[j];
    atomicAdd(&s_hist[f2key(v.x) >> 20], 1u);
    atomicAdd(&s_hist[f2key(v.y) >> 20], 1u);
    atomicAdd(&s_hist[f2key(v.z) >> 20], 1u);
    atomicAdd(&s_hist[f2key(v.w) >> 20], 1u);
  }
  __syncthreads();

  suffix_find(s_hist, k, tid, s_part, &s_b1, &s_a1);
  const unsigned keyFloor1 = (unsigned)s_b1 << 20;
  const int A1 = s_a1;

  // ---- Pass 2: collect candidates; scan q for exact zeros.
  // np semantics: ratio_i = probs_i / q_i is NaN iff probs_i == 0 (masked by
  // top-k/top-p, or underflowed survivor) AND q_i == 0. numpy argmax returns
  // the FIRST NaN index if any NaN exists (NaN beats +inf and all finites).
  const float4* qrow4 = (const float4*)qrow;
  for (int j = tid; j < n4; j += NT) {
    float4 v = lrow4[j];
    float4 qv = qrow4[j];
    int base = j << 2;
    float xs[4] = {v.x, v.y, v.z, v.w};
    float qs[4] = {qv.x, qv.y, qv.z, qv.w};
    #pragma unroll
    for (int t = 0; t < 4; ++t) {
      unsigned kb = f2key(xs[t]);
      if (kb >= keyFloor1) {
        int pos = atomicAdd(&s_cnt, 1);
        if (pos < CAP) s_cand[pos] = ((unsigned long long)kb << 32) | (unsigned)(base + t);
      }
      if (qs[t] == 0.0f) {
        int zp = atomicAdd(&s_nzq, 1);
        if (zp < ZCAP) s_zq[zp] = base + t;
      }
    }
  }
  __syncthreads();
  int C = s_cnt; if (C > CAP) C = CAP;

  // ---- Level-2 refinement within bin B1 ----
  for (int b = tid; b < NBIN; b += NT) s_hist[b] = 0;
  __syncthreads();
  for (int j = tid; j < C; j += NT) {
    unsigned kb = (unsigned)(s_cand[j] >> 32);
    if ((kb >> 20) == (unsigned)s_b1) atomicAdd(&s_hist[(kb >> 8) & 0xFFFu], 1u);
  }
  __syncthreads();
  suffix_find(s_hist, k - A1, tid, s_part, &s_b2, &s_a2);
  const unsigned keyFloor2 = keyFloor1 | ((unsigned)s_b2 << 8);

  // ---- Compact sort set: key >= keyFloor2 (superset of top-k) ----
  for (int j = tid; j < C; j += NT) {
    unsigned long long cd = s_cand[j];
    if ((unsigned)(cd >> 32) >= keyFloor2) {
      int pos = atomicAdd(&s_cnt2, 1);
      if (pos < KCAP) s_kept[pos] = cd;
    }
  }
  __syncthreads();
  int K2 = s_cnt2; if (K2 > KCAP) K2 = KCAP;
  if (K2 < 1) K2 = 1;

  // ---- Bitonic sort KCAP u64 ascending (stable (value, idx)) ----
  for (int j = K2 + tid; j < KCAP; j += NT) s_kept[j] = 0xFFFFFFFFFFFFFFFFull;
  __syncthreads();
  for (int sz = 2; sz <= KCAP; sz <<= 1) {
    for (int st = sz >> 1; st > 0; st >>= 1) {
      for (int i = tid; i < KCAP; i += NT) {
        int j = i ^ st;
        if (j > i) {
          unsigned long long a = s_kept[i], b = s_kept[j];
          bool up = ((i & sz) == 0);
          if ((a > b) == up) { s_kept[i] = b; s_kept[j] = a; }
        }
      }
      __syncthreads();
    }
  }

  // ---- top-k threshold by value (keeps duplicates, like ref) ----
  if (tid == 0) {
    int posk = K2 - k;
    if (posk < 0) posk = 0;
    unsigned tkey = (unsigned)(s_kept[posk] >> 32);
    int s = posk;
    while (s > 0 && (unsigned)(s_kept[s - 1] >> 32) == tkey) --s;
    s_start = s;
  }
  __syncthreads();
  const int start = s_start;
  const float m = key2f((unsigned)(s_kept[K2 - 1] >> 32));   // row max

  // ---- e_j = exp(x - m) for kept values ----
  float* s_e = (float*)s_hist;
  for (int j = start + tid; j < K2; j += NT)
    s_e[j] = expf(key2f((unsigned)(s_kept[j] >> 32)) - m);
  __syncthreads();

  // ---- sequential f32 Z, cumsum (ref order), jstar, Z2, NaN winner ----
  if (tid == 0) {
    float Z = 0.0f;
    for (int j = start; j < K2; ++j) Z += s_e[j];
    float c = 0.0f;
    int js = K2 - 1;
    for (int j = start; j < K2; ++j) {
      c += s_e[j] / Z;
      if (c > oneMinusP) { js = j; break; }
    }
    s_jstar = js;
    float Z2 = 0.0f;
    for (int j = js; j < K2; ++j) Z2 += s_e[j];
    s_Z2 = Z2;

    // First-NaN winner (CLEAN this time — R7's mechanism without the patch
    // stacking that corrupted it): z is NaN iff q_z == 0 AND prob_z == 0
    // (z not a top-p survivor, or survivor with underflowed e).
    int nanIdx = 0x7FFFFFFF;
    int nz = s_nzq; if (nz > ZCAP) nz = ZCAP;
    for (int t = 0; t < nz; ++t) {
      int z = s_zq[t];
      bool surv = false; float ez = 0.0f;
      for (int j = js; j < K2; ++j) {
        if ((int)(unsigned)(s_kept[j] & 0xFFFFFFFFu) == z) { surv = true; ez = s_e[j]; break; }
      }
      if ((!surv || ez == 0.0f) && z < nanIdx) nanIdx = z;
    }
    s_nanIdx = nanIdx;
  }
  __syncthreads();
  const int jstar = s_jstar;
  const float Z2 = s_Z2;

  // ---- argmax over survivors of (e/Z2)/q, lowest-index ties ----
  // (survivor with q==0 && e>0 -> +inf: float compare handles; NaN ratios
  // (e==0 && q==0) are skipped by the > compare, handled via s_nanIdx.)
  float* s_red_v = (float*)(s_hist + 2048);
  int*   s_red_i = (int*)  (s_hist + 3072);
  float bf = -1.0f; int bi = 0x7FFFFFFF;
  for (int j = jstar + tid; j < K2; j += NT) {
    unsigned long long cd = s_kept[j];
    int idx = (int)(unsigned)(cd & 0xFFFFFFFFu);
    if (idx < 0 || idx >= V) continue;
    float ratio = (s_e[j] / Z2) / qrow[idx];
    if (ratio > bf || (ratio == bf && idx < bi)) { bf = ratio; bi = idx; }
  }
  s_red_v[tid] = bf; s_red_i[tid] = bi;
  __syncthreads();
  for (int off = NT / 2; off > 0; off >>= 1) {
    if (tid < off) {
      float of = s_red_v[tid + off]; int oi = s_red_i[tid + off];
      if (of > s_red_v[tid] || (of == s_red_v[tid] && oi < s_red_i[tid])) {
        s_red_v[tid] = of; s_red_i[tid] = oi;
      }
    }
    __syncthreads();
  }
  if (tid == 0) {
    int w;
    if (s_nanIdx != 0x7FFFFFFF) {
      w = s_nanIdx;          // numpy argmax: first NaN wins. NO patches on top.
    } else {
      w = s_red_i[0];
      if (w < 0) w = 0;
      if (w >= V) w = V - 1;
    }
    out[r] = w;
  }
}

extern "C" void kernel_launch(void* const* d_in, const int* in_sizes, int n_in,
                              void* d_out, int out_size, void* d_ws, size_t ws_size,
                              hipStream_t stream) {
  const float* logits = (const float*)d_in[0];
  const void*  kraw   = d_in[1];
  const float* parr   = (const float*)d_in[2];
  const float* qarr   = (const float*)d_in[3];
  int* out = (int*)d_out;
  const int B = out_size;              // one index per row (== 128)
  const int V = in_sizes[0] / B;
  hipLaunchKernelGGL(topk_topp_sample_kernel, dim3(B), dim3(NT), 0, stream,
                     logits, kraw, parr, qarr, out, V);
}